// Round 1
// baseline (612.685 us; speedup 1.0000x reference)
//
#include <hip/hip_runtime.h>
#include <hip/hip_bf16.h>

typedef unsigned short u16;
typedef __attribute__((ext_vector_type(4))) float f32x4;
typedef __attribute__((ext_vector_type(8))) __bf16 bf16x8;

#define DEV __device__ __forceinline__

DEV u16 f2bf(float f) {
  union { float f; unsigned u; } c; c.f = f;
  unsigned r = (c.u + 0x7fffu + ((c.u >> 16) & 1u)) >> 16;
  return (u16)r;
}

DEV void gld_lds16(const void* g, void* l) {
  __builtin_amdgcn_global_load_lds(
      (__attribute__((address_space(1))) void*)g,
      (__attribute__((address_space(3))) void*)l, 16, 0, 0);
}

DEV f32x4 mfma_bf16(bf16x8 a, bf16x8 b, f32x4 c) {
  return __builtin_amdgcn_mfma_f32_16x16x32_bf16(a, b, c, 0, 0, 0);
}

// ---------------- convert f32 -> bf16 (vectorized) ----------------
__global__ __launch_bounds__(256) void cvt_kernel(const float* __restrict__ in,
                                                  u16* __restrict__ out, int n4) {
  int i = blockIdx.x * 256 + threadIdx.x;
  if (i < n4) {
    float4 v = ((const float4*)in)[i];
    ushort4 o;
    o.x = f2bf(v.x); o.y = f2bf(v.y); o.z = f2bf(v.z); o.w = f2bf(v.w);
    ((ushort4*)out)[i] = o;
  }
}

// ------------- transpose + convert: in f32 [bz][R][C] -> out bf16 [bz][C][R] -------------
__global__ __launch_bounds__(256) void transpose_cvt(const float* __restrict__ in,
                                                     u16* __restrict__ out, int R, int C) {
  __shared__ float t[32][33];
  size_t base = (size_t)blockIdx.z * R * C;
  const float* ip = in + base;
  u16* op = out + base;
  int c0 = blockIdx.x * 32, r0 = blockIdx.y * 32;
  int tx = threadIdx.x, ty = threadIdx.y;
#pragma unroll
  for (int i = 0; i < 4; ++i) {
    int rr = ty + i * 8;
    t[rr][tx] = ip[(size_t)(r0 + rr) * C + c0 + tx];
  }
  __syncthreads();
#pragma unroll
  for (int i = 0; i < 4; ++i) {
    int cc = ty + i * 8;
    op[(size_t)(c0 + cc) * R + r0 + tx] = f2bf(t[tx][cc]);
  }
}

// ---------------- generic TN bf16 GEMM: C = A[M,K] * B[N,K]^T ----------------
// MODE 0: q/k epilogue (col=(p,h,e), out bf16 to [B,H,S,D], bias per (h,e))
// MODE 1: vT epilogue (row=(h,e), col=(b,s), out bf16 to [B,H,D,S], bias per row)
// MODE 2: f32 out row-major [M,N] + bias per col
// MODE 3: bf16 out row-major [M,N] + bias + relu
template <int BM, int BN, int WM, int WN, int MODE>
__global__ __launch_bounds__(256) void gemm_tn(const u16* __restrict__ A,
                                               const u16* __restrict__ B, int N, int K,
                                               void* __restrict__ out0, void* __restrict__ out1,
                                               const float* __restrict__ bias0,
                                               const float* __restrict__ bias1) {
  constexpr int BK = 64;
  constexpr int MF = WM / 16, NF = WN / 16;
  constexpr int WC = BN / WN;
  __shared__ u16 As[BM * BK];
  __shared__ u16 Bs[BN * BK];
  const int tid = threadIdx.x;
  const int wave = tid >> 6, lane = tid & 63;
  const int r = lane & 15, g = lane >> 4;
  const int row0 = blockIdx.y * BM, col0 = blockIdx.x * BN;
  const int wr = (wave / WC) * WM, wc = (wave % WC) * WN;

  f32x4 acc[MF][NF] = {};

  for (int kt = 0; kt < K; kt += BK) {
#pragma unroll
    for (int i = 0; i < (BM * BK / 8) / 256; ++i) {
      int c = i * 256 + wave * 64 + lane;
      gld_lds16(A + (size_t)(row0 + (c >> 3)) * K + kt + (c & 7) * 8,
                As + (size_t)(i * 256 + wave * 64) * 8);
    }
#pragma unroll
    for (int i = 0; i < (BN * BK / 8) / 256; ++i) {
      int c = i * 256 + wave * 64 + lane;
      gld_lds16(B + (size_t)(col0 + (c >> 3)) * K + kt + (c & 7) * 8,
                Bs + (size_t)(i * 256 + wave * 64) * 8);
    }
    __syncthreads();
#pragma unroll
    for (int kk = 0; kk < 2; ++kk) {
      bf16x8 af[MF], bfv[NF];
#pragma unroll
      for (int m = 0; m < MF; ++m)
        af[m] = *(const bf16x8*)(As + (wr + m * 16 + r) * BK + kk * 32 + g * 8);
#pragma unroll
      for (int n = 0; n < NF; ++n)
        bfv[n] = *(const bf16x8*)(Bs + (wc + n * 16 + r) * BK + kk * 32 + g * 8);
#pragma unroll
      for (int m = 0; m < MF; ++m)
#pragma unroll
        for (int n = 0; n < NF; ++n)
          acc[m][n] = mfma_bf16(af[m], bfv[n], acc[m][n]);
    }
    __syncthreads();
  }

#pragma unroll
  for (int m = 0; m < MF; ++m) {
#pragma unroll
    for (int n = 0; n < NF; ++n) {
      int gcol = col0 + wc + n * 16 + r;
#pragma unroll
      for (int j = 0; j < 4; ++j) {
        int grow = row0 + wr + m * 16 + g * 4 + j;
        float val = acc[m][n][j];
        if constexpr (MODE == 0) {
          int p = gcol >> 12;
          int he = gcol & 4095;
          u16* dst = (u16*)(p ? out1 : out0);
          const float* bsp = p ? bias1 : bias0;
          val += bsp[he];
          int bb = grow >> 10, s = grow & 1023;
          size_t off = (((size_t)(bb * 8 + (he >> 9)) * 1024 + s) * 512) + (he & 511);
          dst[off] = f2bf(val);
        } else if constexpr (MODE == 1) {
          val += bias0[grow];
          int bb = gcol >> 10, s = gcol & 1023;
          size_t off = (((size_t)bb * 8 + (grow >> 9)) * 512 + (grow & 511)) * 1024 + s;
          ((u16*)out0)[off] = f2bf(val);
        } else if constexpr (MODE == 2) {
          ((float*)out0)[(size_t)grow * N + gcol] = val + bias0[gcol];
        } else {
          float v2 = fmaxf(val + bias0[gcol], 0.0f);
          ((u16*)out0)[(size_t)grow * N + gcol] = f2bf(v2);
        }
      }
    }
  }
  (void)out1; (void)bias1;
}

// ---------------- flash attention ----------------
// grid: 512 blocks = b(4) * h(8) * qt(16); 512 threads = 8 waves
// wave = (qh in 0..1 [32 q-rows each], ei in 0..3 [128 e-cols each])
__global__ __launch_bounds__(512) void flash_kernel(const u16* __restrict__ qg,
                                                    const u16* __restrict__ kg,
                                                    const u16* __restrict__ vtg,
                                                    u16* __restrict__ concat) {
  constexpr float SCALE = 0.04419417382415922f;  // 1/sqrt(512)
  __shared__ u16 Qs[4 * 16 * 64 * 8];   // 64KB, frag-major [mf][kk][lane][8]
  __shared__ u16 Ps[8 * 64 * 8];        // 8KB, frag-major [(qh,m,kk2)][lane][8]
  __shared__ float mpart[2][32][4];
  __shared__ float lpart[2][32][4];

  const int tid = threadIdx.x;
  const int wave = tid >> 6, lane = tid & 63;
  const int r = lane & 15, g = lane >> 4;
  const int qh = wave >> 2, ei = wave & 3;
  const int bx = blockIdx.x;
  const int qt = bx & 15, hh = (bx >> 4) & 7, bb = bx >> 7;
  const size_t hbase = ((size_t)bb * 8 + hh) * 1024 * 512;
  const u16* qp = qg + hbase;
  const u16* kp = kg + hbase;
  const u16* vp = vtg + hbase;  // [512][1024] per head
  const int q0 = qt * 64;

  // stage Q (64 rows x 512) into fragment-major LDS
#pragma unroll
  for (int i = 0; i < 8; ++i) {
    int slotb = wave * 512 + i * 64;
    int slot = slotb + lane;
    int mf = slot >> 10;
    int kk = (slot >> 6) & 15;
    gld_lds16(qp + (size_t)(q0 + mf * 16 + r) * 512 + kk * 32 + g * 8, Qs + (size_t)slotb * 8);
  }

  f32x4 o[2][8] = {};
  float mrun[2][4], lrun[2][4], rs[2][4];
#pragma unroll
  for (int m = 0; m < 2; ++m)
#pragma unroll
    for (int j = 0; j < 4; ++j) { mrun[m][j] = -1e30f; lrun[m][j] = 0.f; }

  __syncthreads();

  for (int kv = 0; kv < 1024; kv += 64) {
    // QK^T: this wave computes S[32 x 16] slice (cols = kv + ei*16 ..)
    f32x4 sacc[2] = {};
#pragma unroll
    for (int kk = 0; kk < 16; ++kk) {
      bf16x8 bk = *(const bf16x8*)(kp + (size_t)(kv + ei * 16 + r) * 512 + kk * 32 + g * 8);
      bf16x8 a0 = *(const bf16x8*)(Qs + ((size_t)((qh * 2 + 0) * 16 + kk) * 64 + lane) * 8);
      bf16x8 a1 = *(const bf16x8*)(Qs + ((size_t)((qh * 2 + 1) * 16 + kk) * 64 + lane) * 8);
      sacc[0] = mfma_bf16(a0, bk, sacc[0]);
      sacc[1] = mfma_bf16(a1, bk, sacc[1]);
    }
    // local row-max over this wave's 16 cols
#pragma unroll
    for (int m = 0; m < 2; ++m) {
#pragma unroll
      for (int j = 0; j < 4; ++j) {
        sacc[m][j] *= SCALE;
        float v = sacc[m][j];
        v = fmaxf(v, __shfl_xor(v, 1));
        v = fmaxf(v, __shfl_xor(v, 2));
        v = fmaxf(v, __shfl_xor(v, 4));
        v = fmaxf(v, __shfl_xor(v, 8));
        if (r == 0) mpart[qh][m * 16 + g * 4 + j][ei] = v;
      }
    }
    __syncthreads();  // bar1: mpart ready
    // combine max across the 4 ei-waves; rescale factors
#pragma unroll
    for (int m = 0; m < 2; ++m) {
#pragma unroll
      for (int j = 0; j < 4; ++j) {
        int lrow = m * 16 + g * 4 + j;
        float4 mm = *(const float4*)&mpart[qh][lrow][0];
        float gm = fmaxf(fmaxf(mm.x, mm.y), fmaxf(mm.z, mm.w));
        float mn = fmaxf(mrun[m][j], gm);
        rs[m][j] = __expf(mrun[m][j] - mn);
        mrun[m][j] = mn;
      }
    }
    // P = exp(s - m), partial l, write P (bf16) into fragment-major LDS
#pragma unroll
    for (int m = 0; m < 2; ++m) {
#pragma unroll
      for (int j = 0; j < 4; ++j) {
        float p = __expf(sacc[m][j] - mrun[m][j]);
        float ls = p;
        ls += __shfl_xor(ls, 1);
        ls += __shfl_xor(ls, 2);
        ls += __shfl_xor(ls, 4);
        ls += __shfl_xor(ls, 8);
        if (r == 0) lpart[qh][m * 16 + g * 4 + j][ei] = ls;
        int pcol = ei * 16 + r;
        int kk2 = pcol >> 5;
        int gg = (pcol >> 3) & 3;
        Ps[((size_t)((qh * 2 + m) * 2 + kk2) * 64 + gg * 16 + (g * 4 + j)) * 8 + (pcol & 7)] =
            f2bf(p);
      }
    }
    __syncthreads();  // bar2: Ps + lpart ready
    // l update + O rescale
#pragma unroll
    for (int m = 0; m < 2; ++m) {
#pragma unroll
      for (int j = 0; j < 4; ++j) {
        int lrow = m * 16 + g * 4 + j;
        float4 ll = *(const float4*)&lpart[qh][lrow][0];
        lrun[m][j] = lrun[m][j] * rs[m][j] + (ll.x + ll.y + ll.z + ll.w);
      }
#pragma unroll
      for (int n = 0; n < 8; ++n)
#pragma unroll
        for (int j = 0; j < 4; ++j) o[m][n][j] *= rs[m][j];
    }
    // PV: O[32 x 128 e-slice] += P[32 x 64] * V[64 x e-slice]
#pragma unroll
    for (int kk2 = 0; kk2 < 2; ++kk2) {
      bf16x8 pa0 = *(const bf16x8*)(Ps + ((size_t)((qh * 2 + 0) * 2 + kk2) * 64 + lane) * 8);
      bf16x8 pa1 = *(const bf16x8*)(Ps + ((size_t)((qh * 2 + 1) * 2 + kk2) * 64 + lane) * 8);
#pragma unroll
      for (int n = 0; n < 8; ++n) {
        bf16x8 bv =
            *(const bf16x8*)(vp + (size_t)(ei * 128 + n * 16 + r) * 1024 + kv + kk2 * 32 + g * 8);
        o[0][n] = mfma_bf16(pa0, bv, o[0][n]);
        o[1][n] = mfma_bf16(pa1, bv, o[1][n]);
      }
    }
  }
  // normalize and write concat [B*S, H*512] bf16
#pragma unroll
  for (int m = 0; m < 2; ++m) {
#pragma unroll
    for (int j = 0; j < 4; ++j) {
      float inv = 1.0f / lrun[m][j];
      int srow = q0 + qh * 32 + m * 16 + g * 4 + j;
      size_t rowoff = ((size_t)bb * 1024 + srow) * 4096;
#pragma unroll
      for (int n = 0; n < 8; ++n) {
        int ocol = hh * 512 + ei * 128 + n * 16 + r;
        concat[rowoff + ocol] = f2bf(o[m][n][j] * inv);
      }
    }
  }
}

// ---------------- residual add + layernorm (row of 512) ----------------
__global__ __launch_bounds__(128) void add_ln_kernel(const float* __restrict__ xin,
                                                     const float* __restrict__ addin,
                                                     const float* __restrict__ gamma,
                                                     const float* __restrict__ beta,
                                                     float* __restrict__ yout,
                                                     u16* __restrict__ ybout) {
  int row = blockIdx.x;
  int t = threadIdx.x;
  float4 xv = ((const float4*)(xin + (size_t)row * 512))[t];
  float4 av = ((const float4*)(addin + (size_t)row * 512))[t];
  float v0 = xv.x + av.x, v1 = xv.y + av.y, v2 = xv.z + av.z, v3 = xv.w + av.w;
  float s1 = v0 + v1 + v2 + v3;
  float s2 = v0 * v0 + v1 * v1 + v2 * v2 + v3 * v3;
#pragma unroll
  for (int d = 1; d < 64; d <<= 1) {
    s1 += __shfl_xor(s1, d);
    s2 += __shfl_xor(s2, d);
  }
  __shared__ float sh[4];
  int wv = t >> 6;
  if ((t & 63) == 0) { sh[wv * 2] = s1; sh[wv * 2 + 1] = s2; }
  __syncthreads();
  s1 = sh[0] + sh[2];
  s2 = sh[1] + sh[3];
  float mean = s1 * (1.0f / 512.0f);
  float var = s2 * (1.0f / 512.0f) - mean * mean;
  float rstd = rsqrtf(var + 1e-6f);
  float4 gv = ((const float4*)gamma)[t];
  float4 bv = ((const float4*)beta)[t];
  float o0 = (v0 - mean) * rstd * gv.x + bv.x;
  float o1 = (v1 - mean) * rstd * gv.y + bv.y;
  float o2 = (v2 - mean) * rstd * gv.z + bv.z;
  float o3 = (v3 - mean) * rstd * gv.w + bv.w;
  float4 ov; ov.x = o0; ov.y = o1; ov.z = o2; ov.w = o3;
  ((float4*)(yout + (size_t)row * 512))[t] = ov;
  if (ybout) {
    ushort4 ub;
    ub.x = f2bf(o0); ub.y = f2bf(o1); ub.z = f2bf(o2); ub.w = f2bf(o3);
    ((ushort4*)(ybout + (size_t)row * 512))[t] = ub;
  }
}

extern "C" void kernel_launch(void* const* d_in, const int* in_sizes, int n_in, void* d_out,
                              int out_size, void* d_ws, size_t ws_size, hipStream_t stream) {
  (void)in_sizes; (void)n_in; (void)out_size; (void)ws_size;
  const float* x   = (const float*)d_in[0];
  const float* Wq  = (const float*)d_in[1];
  const float* bq  = (const float*)d_in[2];
  const float* Wk  = (const float*)d_in[3];
  const float* bk  = (const float*)d_in[4];
  const float* Wv  = (const float*)d_in[5];
  const float* bv  = (const float*)d_in[6];
  const float* Wo  = (const float*)d_in[7];
  const float* bo  = (const float*)d_in[8];
  const float* g1  = (const float*)d_in[9];
  const float* be1 = (const float*)d_in[10];
  const float* W1  = (const float*)d_in[11];
  const float* b1  = (const float*)d_in[12];
  const float* W2  = (const float*)d_in[13];
  const float* b2  = (const float*)d_in[14];
  const float* g2  = (const float*)d_in[15];
  const float* be2 = (const float*)d_in[16];

  char* ws = (char*)d_ws;
  const size_t MB = 1024 * 1024;
  u16*   xb   = (u16*)(ws + 0);
  u16*   wqkT = (u16*)(ws + 4 * MB);
  u16*   wvT  = (u16*)(ws + 12 * MB);
  u16*   woT  = (u16*)(ws + 16 * MB);
  u16*   w1T  = (u16*)(ws + 20 * MB);
  u16*   w2T  = (u16*)(ws + 22 * MB);
  u16*   qb   = (u16*)(ws + 24 * MB);
  u16*   kb   = (u16*)(ws + 56 * MB);
  u16*   vTb  = (u16*)(ws + 88 * MB);
  u16*   cc   = (u16*)(ws + 120 * MB);
  float* mha  = (float*)(ws + 24 * MB);  // reuse q region after attention
  float* y    = (float*)(ws + 32 * MB);
  u16*   yb   = (u16*)(ws + 40 * MB);
  u16*   ff1  = (u16*)(ws + 56 * MB);    // reuse k region
  float* ff2  = (float*)(ws + 72 * MB);

  cvt_kernel<<<2048, 256, 0, stream>>>(x, xb, 524288);
  transpose_cvt<<<dim3(16, 16, 8), dim3(32, 8), 0, stream>>>(Wq, wqkT, 512, 512);
  transpose_cvt<<<dim3(16, 16, 8), dim3(32, 8), 0, stream>>>(Wk, wqkT + 8 * 512 * 512, 512, 512);
  transpose_cvt<<<dim3(16, 16, 8), dim3(32, 8), 0, stream>>>(Wv, wvT, 512, 512);
  transpose_cvt<<<dim3(16, 128, 1), dim3(32, 8), 0, stream>>>(Wo, woT, 4096, 512);
  transpose_cvt<<<dim3(64, 16, 1), dim3(32, 8), 0, stream>>>(W1, w1T, 512, 2048);
  transpose_cvt<<<dim3(16, 64, 1), dim3(32, 8), 0, stream>>>(W2, w2T, 2048, 512);

  // Q,K projections: M=4096, N=8192 (p,h,e), K=512
  gemm_tn<128, 128, 64, 64, 0><<<dim3(64, 32), 256, 0, stream>>>(xb, wqkT, 8192, 512, qb, kb, bq, bk);
  // V^T: A=WvT[(h,e),d], B=xb[(b,s),d] -> vT[b,h,e,s]
  gemm_tn<128, 128, 64, 64, 1><<<dim3(32, 32), 256, 0, stream>>>(wvT, xb, 4096, 512, vTb, nullptr, bv, nullptr);
  // attention
  flash_kernel<<<512, 512, 0, stream>>>(qb, kb, vTb, cc);
  // output projection: M=4096, N=512, K=4096
  gemm_tn<64, 128, 32, 64, 2><<<dim3(4, 64), 256, 0, stream>>>(cc, woT, 512, 4096, mha, nullptr, bo, nullptr);
  add_ln_kernel<<<4096, 128, 0, stream>>>(x, mha, g1, be1, y, yb);
  // FFN
  gemm_tn<128, 128, 64, 64, 3><<<dim3(16, 32), 256, 0, stream>>>(yb, w1T, 2048, 512, ff1, nullptr, b1, nullptr);
  gemm_tn<64, 128, 32, 64, 2><<<dim3(4, 64), 256, 0, stream>>>(ff1, w2T, 512, 2048, ff2, nullptr, b2, nullptr);
  add_ln_kernel<<<4096, 128, 0, stream>>>(y, ff2, g2, be2, (float*)d_out, nullptr);
}

// Round 2
// 493.468 us; speedup vs baseline: 1.2416x; 1.2416x over previous
//
#include <hip/hip_runtime.h>
#include <hip/hip_bf16.h>

typedef unsigned short u16;
typedef __attribute__((ext_vector_type(4))) float f32x4;
typedef __attribute__((ext_vector_type(8))) __bf16 bf16x8;

#define DEV __device__ __forceinline__

DEV u16 f2bf(float f) {
  union { float f; unsigned u; } c; c.f = f;
  unsigned r = (c.u + 0x7fffu + ((c.u >> 16) & 1u)) >> 16;
  return (u16)r;
}

DEV void gld_lds16(const void* g, void* l) {
  __builtin_amdgcn_global_load_lds(
      (__attribute__((address_space(1))) void*)g,
      (__attribute__((address_space(3))) void*)l, 16, 0, 0);
}

DEV f32x4 mfma_bf16(bf16x8 a, bf16x8 b, f32x4 c) {
  return __builtin_amdgcn_mfma_f32_16x16x32_bf16(a, b, c, 0, 0, 0);
}

// ---------------- convert f32 -> bf16 (vectorized) ----------------
__global__ __launch_bounds__(256) void cvt_kernel(const float* __restrict__ in,
                                                  u16* __restrict__ out, int n4) {
  int i = blockIdx.x * 256 + threadIdx.x;
  if (i < n4) {
    float4 v = ((const float4*)in)[i];
    ushort4 o;
    o.x = f2bf(v.x); o.y = f2bf(v.y); o.z = f2bf(v.z); o.w = f2bf(v.w);
    ((ushort4*)out)[i] = o;
  }
}

// ------------- transpose + convert: in f32 [bz][R][C] -> out bf16 [bz][C][R] -------------
__global__ __launch_bounds__(256) void transpose_cvt(const float* __restrict__ in,
                                                     u16* __restrict__ out, int R, int C) {
  __shared__ float t[32][33];
  size_t base = (size_t)blockIdx.z * R * C;
  const float* ip = in + base;
  u16* op = out + base;
  int c0 = blockIdx.x * 32, r0 = blockIdx.y * 32;
  int tx = threadIdx.x, ty = threadIdx.y;
#pragma unroll
  for (int i = 0; i < 4; ++i) {
    int rr = ty + i * 8;
    t[rr][tx] = ip[(size_t)(r0 + rr) * C + c0 + tx];
  }
  __syncthreads();
#pragma unroll
  for (int i = 0; i < 4; ++i) {
    int cc = ty + i * 8;
    op[(size_t)(c0 + cc) * R + r0 + tx] = f2bf(t[tx][cc]);
  }
}

// ---------------- generic TN bf16 GEMM: C = A[M,K] * B[N,K]^T ----------------
template <int BM, int BN, int WM, int WN, int MODE>
__global__ __launch_bounds__(256) void gemm_tn(const u16* __restrict__ A,
                                               const u16* __restrict__ B, int N, int K,
                                               void* __restrict__ out0, void* __restrict__ out1,
                                               const float* __restrict__ bias0,
                                               const float* __restrict__ bias1) {
  constexpr int BK = 64;
  constexpr int MF = WM / 16, NF = WN / 16;
  constexpr int WC = BN / WN;
  __shared__ u16 As[BM * BK];
  __shared__ u16 Bs[BN * BK];
  const int tid = threadIdx.x;
  const int wave = tid >> 6, lane = tid & 63;
  const int r = lane & 15, g = lane >> 4;
  const int row0 = blockIdx.y * BM, col0 = blockIdx.x * BN;
  const int wr = (wave / WC) * WM, wc = (wave % WC) * WN;

  f32x4 acc[MF][NF] = {};

  for (int kt = 0; kt < K; kt += BK) {
#pragma unroll
    for (int i = 0; i < (BM * BK / 8) / 256; ++i) {
      int c = i * 256 + wave * 64 + lane;
      gld_lds16(A + (size_t)(row0 + (c >> 3)) * K + kt + (c & 7) * 8,
                As + (size_t)(i * 256 + wave * 64) * 8);
    }
#pragma unroll
    for (int i = 0; i < (BN * BK / 8) / 256; ++i) {
      int c = i * 256 + wave * 64 + lane;
      gld_lds16(B + (size_t)(col0 + (c >> 3)) * K + kt + (c & 7) * 8,
                Bs + (size_t)(i * 256 + wave * 64) * 8);
    }
    __syncthreads();
#pragma unroll
    for (int kk = 0; kk < 2; ++kk) {
      bf16x8 af[MF], bfv[NF];
#pragma unroll
      for (int m = 0; m < MF; ++m)
        af[m] = *(const bf16x8*)(As + (wr + m * 16 + r) * BK + kk * 32 + g * 8);
#pragma unroll
      for (int n = 0; n < NF; ++n)
        bfv[n] = *(const bf16x8*)(Bs + (wc + n * 16 + r) * BK + kk * 32 + g * 8);
#pragma unroll
      for (int m = 0; m < MF; ++m)
#pragma unroll
        for (int n = 0; n < NF; ++n)
          acc[m][n] = mfma_bf16(af[m], bfv[n], acc[m][n]);
    }
    __syncthreads();
  }

#pragma unroll
  for (int m = 0; m < MF; ++m) {
#pragma unroll
    for (int n = 0; n < NF; ++n) {
      int gcol = col0 + wc + n * 16 + r;
#pragma unroll
      for (int j = 0; j < 4; ++j) {
        int grow = row0 + wr + m * 16 + g * 4 + j;
        float val = acc[m][n][j];
        if constexpr (MODE == 0) {
          int p = gcol >> 12;
          int he = gcol & 4095;
          u16* dst = (u16*)(p ? out1 : out0);
          const float* bsp = p ? bias1 : bias0;
          val += bsp[he];
          int bb = grow >> 10, s = grow & 1023;
          size_t off = (((size_t)(bb * 8 + (he >> 9)) * 1024 + s) * 512) + (he & 511);
          dst[off] = f2bf(val);
        } else if constexpr (MODE == 1) {
          val += bias0[grow];
          int bb = gcol >> 10, s = gcol & 1023;
          size_t off = (((size_t)bb * 8 + (grow >> 9)) * 512 + (grow & 511)) * 1024 + s;
          ((u16*)out0)[off] = f2bf(val);
        } else if constexpr (MODE == 2) {
          ((float*)out0)[(size_t)grow * N + gcol] = val + bias0[gcol];
        } else {
          float v2 = fmaxf(val + bias0[gcol], 0.0f);
          ((u16*)out0)[(size_t)grow * N + gcol] = f2bf(v2);
        }
      }
    }
  }
  (void)out1; (void)bias1;
}

// ---------------- flash attention (v2) ----------------
// 512 blocks, XCD-swizzled: xcd=bx&7 -> 4 heads x 16 qtiles per XCD.
// 8 waves = qh(4, 16 q-rows each) x ei(2: kv-half for QK^T, e-half 256 for PV).
// Q in registers; K,V tiles (KVB=32) double-buffered in LDS via global_load_lds.
__global__ __launch_bounds__(512) void flash_kernel(const u16* __restrict__ qg,
                                                    const u16* __restrict__ kg,
                                                    const u16* __restrict__ vtg,
                                                    u16* __restrict__ concat) {
  constexpr float SCALE = 0.04419417382415922f;  // 1/sqrt(512)
  __shared__ u16 Ks[2][16 * 2 * 64 * 8];  // 32KB x2, frag-major [kk][f][lane][8]
  __shared__ u16 Vs[2][32 * 64 * 8];      // 32KB x2, frag-major [n][lane][8]
  __shared__ u16 Ps[4 * 64 * 8];          // 4KB, frag-major [qh][lane][8]
  __shared__ float mpart[4][16][2];
  __shared__ float lpart[4][16][2];

  const int tid = threadIdx.x;
  const int wave = tid >> 6, lane = tid & 63;
  const int r = lane & 15, g = lane >> 4;
  const int qh = wave >> 1, ei = wave & 1;
  const int bx = blockIdx.x;
  const int xcd = bx & 7, slot = bx >> 3;
  const int bh = xcd * 4 + (slot >> 4);
  const int qt = slot & 15;
  const int bb = bh >> 3, hh = bh & 7;
  const size_t hbase = (size_t)bh * 1024 * 512;
  const u16* qp = qg + hbase;
  const u16* kp = kg + hbase;
  const u16* vp = vtg + hbase;  // V^T [512][1024] per head
  const int q0 = qt * 64;

  // Q into registers: rows q0+qh*16+r, all 512 K-elems
  bf16x8 q[16];
#pragma unroll
  for (int kk = 0; kk < 16; ++kk)
    q[kk] = *(const bf16x8*)(qp + (size_t)(q0 + qh * 16 + r) * 512 + kk * 32 + g * 8);

  // stage K,V tile t into buffer p: 64 gld_lds16 insts, 8 per wave
  auto stageKV = [&](int t, int p) {
    int kv = t * 32;
#pragma unroll
    for (int j = 0; j < 4; ++j) {
      int id = wave * 4 + j;
      int kk = id >> 1, f = id & 1;
      gld_lds16(kp + (size_t)(kv + f * 16 + r) * 512 + kk * 32 + g * 8,
                &Ks[p][(kk * 2 + f) * 64 * 8]);
    }
#pragma unroll
    for (int j = 0; j < 4; ++j) {
      int n = wave * 4 + j;
      gld_lds16(vp + (size_t)(n * 16 + r) * 1024 + kv + g * 8, &Vs[p][n * 64 * 8]);
    }
  };

  f32x4 o[16] = {};
  float mrun[4], lrun[4], rs[4];
#pragma unroll
  for (int j = 0; j < 4; ++j) { mrun[j] = -1e30f; lrun[j] = 0.f; }

  stageKV(0, 0);
  __syncthreads();

  for (int t = 0; t < 32; ++t) {
    const int p = t & 1;
    if (t < 31) stageKV(t + 1, p ^ 1);
    // QK^T: S[16q x 16kv] for this wave's ei kv-half; two 8-deep chains
    f32x4 s0 = {}, s1 = {};
#pragma unroll
    for (int kk = 0; kk < 8; ++kk) {
      bf16x8 bk0 = *(const bf16x8*)&Ks[p][(((2 * kk) * 2 + ei) * 64 + lane) * 8];
      bf16x8 bk1 = *(const bf16x8*)&Ks[p][(((2 * kk + 1) * 2 + ei) * 64 + lane) * 8];
      s0 = mfma_bf16(q[2 * kk], bk0, s0);
      s1 = mfma_bf16(q[2 * kk + 1], bk1, s1);
    }
    f32x4 sacc = s0 + s1;
    // partial row-max over this wave's 16 kv-cols
#pragma unroll
    for (int j = 0; j < 4; ++j) {
      sacc[j] *= SCALE;
      float v = sacc[j];
      v = fmaxf(v, __shfl_xor(v, 1));
      v = fmaxf(v, __shfl_xor(v, 2));
      v = fmaxf(v, __shfl_xor(v, 4));
      v = fmaxf(v, __shfl_xor(v, 8));
      if (r == 0) mpart[qh][g * 4 + j][ei] = v;
    }
    __syncthreads();  // bar1 (also drains stage vmcnt)
#pragma unroll
    for (int j = 0; j < 4; ++j) {
      float gm = fmaxf(mpart[qh][g * 4 + j][0], mpart[qh][g * 4 + j][1]);
      float mn = fmaxf(mrun[j], gm);
      rs[j] = __expf(mrun[j] - mn);
      mrun[j] = mn;
      float pv = __expf(sacc[j] - mn);
      float ls = pv;
      ls += __shfl_xor(ls, 1);
      ls += __shfl_xor(ls, 2);
      ls += __shfl_xor(ls, 4);
      ls += __shfl_xor(ls, 8);
      if (r == 0) lpart[qh][g * 4 + j][ei] = ls;
      // P into frag-major Ps: row=g*4+j, col=ei*16+r
      Ps[((size_t)qh * 64 + (ei * 2 + (r >> 3)) * 16 + g * 4 + j) * 8 + (r & 7)] = f2bf(pv);
    }
    __syncthreads();  // bar2: Ps + lpart ready
#pragma unroll
    for (int j = 0; j < 4; ++j)
      lrun[j] = lrun[j] * rs[j] + lpart[qh][g * 4 + j][0] + lpart[qh][g * 4 + j][1];
#pragma unroll
    for (int n = 0; n < 16; ++n)
#pragma unroll
      for (int j = 0; j < 4; ++j) o[n][j] *= rs[j];
    // PV: o[16q x 256e half] += P[16q x 32kv] * V
    bf16x8 pa = *(const bf16x8*)&Ps[((size_t)qh * 64 + lane) * 8];
#pragma unroll
    for (int n = 0; n < 16; ++n) {
      bf16x8 bv = *(const bf16x8*)&Vs[p][((ei * 16 + n) * 64 + lane) * 8];
      o[n] = mfma_bf16(pa, bv, o[n]);
    }
    __syncthreads();  // bar3: done with Ks[p],Vs[p],Ps; stage(t+1) drained
  }

  // normalize + write concat [B*S, 4096]
#pragma unroll
  for (int j = 0; j < 4; ++j) {
    float inv = 1.0f / lrun[j];
    int srow = q0 + qh * 16 + g * 4 + j;
    size_t rowoff = ((size_t)bb * 1024 + srow) * 4096;
#pragma unroll
    for (int n = 0; n < 16; ++n) {
      int ocol = hh * 512 + ei * 256 + n * 16 + r;
      concat[rowoff + ocol] = f2bf(o[n][j] * inv);
    }
  }
}

// ---------------- residual add + layernorm (row of 512) ----------------
__global__ __launch_bounds__(128) void add_ln_kernel(const float* __restrict__ xin,
                                                     const float* __restrict__ addin,
                                                     const float* __restrict__ gamma,
                                                     const float* __restrict__ beta,
                                                     float* __restrict__ yout,
                                                     u16* __restrict__ ybout) {
  int row = blockIdx.x;
  int t = threadIdx.x;
  float4 xv = ((const float4*)(xin + (size_t)row * 512))[t];
  float4 av = ((const float4*)(addin + (size_t)row * 512))[t];
  float v0 = xv.x + av.x, v1 = xv.y + av.y, v2 = xv.z + av.z, v3 = xv.w + av.w;
  float s1 = v0 + v1 + v2 + v3;
  float s2 = v0 * v0 + v1 * v1 + v2 * v2 + v3 * v3;
#pragma unroll
  for (int d = 1; d < 64; d <<= 1) {
    s1 += __shfl_xor(s1, d);
    s2 += __shfl_xor(s2, d);
  }
  __shared__ float sh[4];
  int wv = t >> 6;
  if ((t & 63) == 0) { sh[wv * 2] = s1; sh[wv * 2 + 1] = s2; }
  __syncthreads();
  s1 = sh[0] + sh[2];
  s2 = sh[1] + sh[3];
  float mean = s1 * (1.0f / 512.0f);
  float var = s2 * (1.0f / 512.0f) - mean * mean;
  float rstd = rsqrtf(var + 1e-6f);
  float4 gv = ((const float4*)gamma)[t];
  float4 bv = ((const float4*)beta)[t];
  float o0 = (v0 - mean) * rstd * gv.x + bv.x;
  float o1 = (v1 - mean) * rstd * gv.y + bv.y;
  float o2 = (v2 - mean) * rstd * gv.z + bv.z;
  float o3 = (v3 - mean) * rstd * gv.w + bv.w;
  float4 ov; ov.x = o0; ov.y = o1; ov.z = o2; ov.w = o3;
  ((float4*)(yout + (size_t)row * 512))[t] = ov;
  if (ybout) {
    ushort4 ub;
    ub.x = f2bf(o0); ub.y = f2bf(o1); ub.z = f2bf(o2); ub.w = f2bf(o3);
    ((ushort4*)(ybout + (size_t)row * 512))[t] = ub;
  }
}

extern "C" void kernel_launch(void* const* d_in, const int* in_sizes, int n_in, void* d_out,
                              int out_size, void* d_ws, size_t ws_size, hipStream_t stream) {
  (void)in_sizes; (void)n_in; (void)out_size; (void)ws_size;
  const float* x   = (const float*)d_in[0];
  const float* Wq  = (const float*)d_in[1];
  const float* bq  = (const float*)d_in[2];
  const float* Wk  = (const float*)d_in[3];
  const float* bk  = (const float*)d_in[4];
  const float* Wv  = (const float*)d_in[5];
  const float* bv  = (const float*)d_in[6];
  const float* Wo  = (const float*)d_in[7];
  const float* bo  = (const float*)d_in[8];
  const float* g1  = (const float*)d_in[9];
  const float* be1 = (const float*)d_in[10];
  const float* W1  = (const float*)d_in[11];
  const float* b1  = (const float*)d_in[12];
  const float* W2  = (const float*)d_in[13];
  const float* b2  = (const float*)d_in[14];
  const float* g2  = (const float*)d_in[15];
  const float* be2 = (const float*)d_in[16];

  char* ws = (char*)d_ws;
  const size_t MB = 1024 * 1024;
  u16*   xb   = (u16*)(ws + 0);
  u16*   wqkT = (u16*)(ws + 4 * MB);
  u16*   wvT  = (u16*)(ws + 12 * MB);
  u16*   woT  = (u16*)(ws + 16 * MB);
  u16*   w1T  = (u16*)(ws + 20 * MB);
  u16*   w2T  = (u16*)(ws + 22 * MB);
  u16*   qb   = (u16*)(ws + 24 * MB);
  u16*   kb   = (u16*)(ws + 56 * MB);
  u16*   vTb  = (u16*)(ws + 88 * MB);
  u16*   cc   = (u16*)(ws + 120 * MB);
  float* mha  = (float*)(ws + 24 * MB);  // reuse q region after attention
  float* y    = (float*)(ws + 32 * MB);
  u16*   yb   = (u16*)(ws + 40 * MB);
  u16*   ff1  = (u16*)(ws + 56 * MB);    // reuse k region
  float* ff2  = (float*)(ws + 72 * MB);

  cvt_kernel<<<2048, 256, 0, stream>>>(x, xb, 524288);
  transpose_cvt<<<dim3(16, 16, 8), dim3(32, 8), 0, stream>>>(Wq, wqkT, 512, 512);
  transpose_cvt<<<dim3(16, 16, 8), dim3(32, 8), 0, stream>>>(Wk, wqkT + 8 * 512 * 512, 512, 512);
  transpose_cvt<<<dim3(16, 16, 8), dim3(32, 8), 0, stream>>>(Wv, wvT, 512, 512);
  transpose_cvt<<<dim3(16, 128, 1), dim3(32, 8), 0, stream>>>(Wo, woT, 4096, 512);
  transpose_cvt<<<dim3(64, 16, 1), dim3(32, 8), 0, stream>>>(W1, w1T, 512, 2048);
  transpose_cvt<<<dim3(16, 64, 1), dim3(32, 8), 0, stream>>>(W2, w2T, 2048, 512);

  gemm_tn<128, 128, 64, 64, 0><<<dim3(64, 32), 256, 0, stream>>>(xb, wqkT, 8192, 512, qb, kb, bq, bk);
  gemm_tn<128, 128, 64, 64, 1><<<dim3(32, 32), 256, 0, stream>>>(wvT, xb, 4096, 512, vTb, nullptr, bv, nullptr);
  flash_kernel<<<512, 512, 0, stream>>>(qb, kb, vTb, cc);
  gemm_tn<64, 128, 32, 64, 2><<<dim3(4, 64), 256, 0, stream>>>(cc, woT, 512, 4096, mha, nullptr, bo, nullptr);
  add_ln_kernel<<<4096, 128, 0, stream>>>(x, mha, g1, be1, y, yb);
  gemm_tn<128, 128, 64, 64, 3><<<dim3(16, 32), 256, 0, stream>>>(yb, w1T, 2048, 512, ff1, nullptr, b1, nullptr);
  gemm_tn<64, 128, 32, 64, 2><<<dim3(4, 64), 256, 0, stream>>>(ff1, w2T, 512, 2048, ff2, nullptr, b2, nullptr);
  add_ln_kernel<<<4096, 128, 0, stream>>>(y, ff2, g2, be2, (float*)d_out, nullptr);
}

// Round 3
// 401.987 us; speedup vs baseline: 1.5241x; 1.2276x over previous
//
#include <hip/hip_runtime.h>
#include <hip/hip_bf16.h>

typedef unsigned short u16;
typedef __attribute__((ext_vector_type(4))) float f32x4;
typedef __attribute__((ext_vector_type(8))) __bf16 bf16x8;

#define DEV __device__ __forceinline__

DEV u16 f2bf(float f) {
  union { float f; unsigned u; } c; c.f = f;
  unsigned r = (c.u + 0x7fffu + ((c.u >> 16) & 1u)) >> 16;
  return (u16)r;
}

DEV void gld_lds16(const void* g, void* l) {
  __builtin_amdgcn_global_load_lds(
      (__attribute__((address_space(1))) void*)g,
      (__attribute__((address_space(3))) void*)l, 16, 0, 0);
}

DEV f32x4 mfma_bf16(bf16x8 a, bf16x8 b, f32x4 c) {
  return __builtin_amdgcn_mfma_f32_16x16x32_bf16(a, b, c, 0, 0, 0);
}

// raw barriers: do NOT drain vmcnt unless asked (vs __syncthreads which always does)
DEV void bar_vm0() { asm volatile("s_waitcnt vmcnt(0) lgkmcnt(0)\n\ts_barrier" ::: "memory"); }
DEV void bar_lg0() { asm volatile("s_waitcnt lgkmcnt(0)\n\ts_barrier" ::: "memory"); }

// ---------------- convert f32 -> bf16 (vectorized) ----------------
__global__ __launch_bounds__(256) void cvt_kernel(const float* __restrict__ in,
                                                  u16* __restrict__ out, int n4) {
  int i = blockIdx.x * 256 + threadIdx.x;
  if (i < n4) {
    float4 v = ((const float4*)in)[i];
    ushort4 o;
    o.x = f2bf(v.x); o.y = f2bf(v.y); o.z = f2bf(v.z); o.w = f2bf(v.w);
    ((ushort4*)out)[i] = o;
  }
}

// ------------- transpose + convert: in f32 [bz][R][C] -> out bf16 [bz][C][R] -------------
__global__ __launch_bounds__(256) void transpose_cvt(const float* __restrict__ in,
                                                     u16* __restrict__ out, int R, int C) {
  __shared__ float t[32][33];
  size_t base = (size_t)blockIdx.z * R * C;
  const float* ip = in + base;
  u16* op = out + base;
  int c0 = blockIdx.x * 32, r0 = blockIdx.y * 32;
  int tx = threadIdx.x, ty = threadIdx.y;
#pragma unroll
  for (int i = 0; i < 4; ++i) {
    int rr = ty + i * 8;
    t[rr][tx] = ip[(size_t)(r0 + rr) * C + c0 + tx];
  }
  __syncthreads();
#pragma unroll
  for (int i = 0; i < 4; ++i) {
    int cc = ty + i * 8;
    op[(size_t)(c0 + cc) * R + r0 + tx] = f2bf(t[tx][cc]);
  }
}

// ---------------- generic TN bf16 GEMM: C = A[M,K] * B[N,K]^T ----------------
template <int BM, int BN, int WM, int WN, int MODE>
__global__ __launch_bounds__(256) void gemm_tn(const u16* __restrict__ A,
                                               const u16* __restrict__ B, int N, int K,
                                               void* __restrict__ out0, void* __restrict__ out1,
                                               const float* __restrict__ bias0,
                                               const float* __restrict__ bias1) {
  constexpr int BK = 64;
  constexpr int MF = WM / 16, NF = WN / 16;
  constexpr int WC = BN / WN;
  __shared__ u16 As[BM * BK];
  __shared__ u16 Bs[BN * BK];
  const int tid = threadIdx.x;
  const int wave = tid >> 6, lane = tid & 63;
  const int r = lane & 15, g = lane >> 4;
  const int row0 = blockIdx.y * BM, col0 = blockIdx.x * BN;
  const int wr = (wave / WC) * WM, wc = (wave % WC) * WN;

  f32x4 acc[MF][NF] = {};

  for (int kt = 0; kt < K; kt += BK) {
#pragma unroll
    for (int i = 0; i < (BM * BK / 8) / 256; ++i) {
      int c = i * 256 + wave * 64 + lane;
      gld_lds16(A + (size_t)(row0 + (c >> 3)) * K + kt + (c & 7) * 8,
                As + (size_t)(i * 256 + wave * 64) * 8);
    }
#pragma unroll
    for (int i = 0; i < (BN * BK / 8) / 256; ++i) {
      int c = i * 256 + wave * 64 + lane;
      gld_lds16(B + (size_t)(col0 + (c >> 3)) * K + kt + (c & 7) * 8,
                Bs + (size_t)(i * 256 + wave * 64) * 8);
    }
    __syncthreads();
#pragma unroll
    for (int kk = 0; kk < 2; ++kk) {
      bf16x8 af[MF], bfv[NF];
#pragma unroll
      for (int m = 0; m < MF; ++m)
        af[m] = *(const bf16x8*)(As + (wr + m * 16 + r) * BK + kk * 32 + g * 8);
#pragma unroll
      for (int n = 0; n < NF; ++n)
        bfv[n] = *(const bf16x8*)(Bs + (wc + n * 16 + r) * BK + kk * 32 + g * 8);
#pragma unroll
      for (int m = 0; m < MF; ++m)
#pragma unroll
        for (int n = 0; n < NF; ++n)
          acc[m][n] = mfma_bf16(af[m], bfv[n], acc[m][n]);
    }
    __syncthreads();
  }

#pragma unroll
  for (int m = 0; m < MF; ++m) {
#pragma unroll
    for (int n = 0; n < NF; ++n) {
      int gcol = col0 + wc + n * 16 + r;
#pragma unroll
      for (int j = 0; j < 4; ++j) {
        int grow = row0 + wr + m * 16 + g * 4 + j;
        float val = acc[m][n][j];
        if constexpr (MODE == 0) {
          int p = gcol >> 12;
          int he = gcol & 4095;
          u16* dst = (u16*)(p ? out1 : out0);
          const float* bsp = p ? bias1 : bias0;
          val += bsp[he];
          int bb = grow >> 10, s = grow & 1023;
          size_t off = (((size_t)(bb * 8 + (he >> 9)) * 1024 + s) * 512) + (he & 511);
          dst[off] = f2bf(val);
        } else if constexpr (MODE == 1) {
          val += bias0[grow];
          int bb = gcol >> 10, s = gcol & 1023;
          size_t off = (((size_t)bb * 8 + (grow >> 9)) * 512 + (grow & 511)) * 1024 + s;
          ((u16*)out0)[off] = f2bf(val);
        } else if constexpr (MODE == 2) {
          ((float*)out0)[(size_t)grow * N + gcol] = val + bias0[gcol];
        } else {
          float v2 = fmaxf(val + bias0[gcol], 0.0f);
          ((u16*)out0)[(size_t)grow * N + gcol] = f2bf(v2);
        }
      }
    }
  }
  (void)out1; (void)bias1;
}

// ---------------- flash attention (v4) ----------------
// 256 blocks (1/CU, 1 round), XCD-swizzled: 4 heads x 8 qtiles per XCD.
// 8 waves, each owns 16 q-rows x full 512 e-cols; full 32-kv width per iter.
// Softmax entirely in-wave (shfl). Raw barriers keep prefetch loads in flight.
__global__ __launch_bounds__(512, 2) void flash_kernel(const u16* __restrict__ qg,
                                                       const u16* __restrict__ kg,
                                                       const u16* __restrict__ vtg,
                                                       u16* __restrict__ concat) {
  constexpr float SCALE = 0.04419417382415922f;  // 1/sqrt(512)
  __shared__ u16 Ks[2][16 * 2 * 64 * 8];  // 32KB x2: [kk][f][lane][8]
  __shared__ u16 Vs[2][32 * 64 * 8];      // 32KB x2: [n][lane][8]
  __shared__ u16 Ps[8][64 * 8];           // 8KB: per-wave A-frag P[16q x 32kv]

  const int tid = threadIdx.x;
  const int wave = tid >> 6, lane = tid & 63;
  const int r = lane & 15, g = lane >> 4;
  const int bx = blockIdx.x;
  const int xcd = bx & 7, slot = bx >> 3;
  const int bh = xcd * 4 + (slot >> 3);
  const int qt = slot & 7;
  const int bb = bh >> 3, hh = bh & 7;
  const size_t hbase = (size_t)bh * 1024 * 512;
  const u16* qp = qg + hbase;
  const u16* kp = kg + hbase;
  const u16* vp = vtg + hbase;  // V^T [512][1024] per head
  const int q0 = qt * 128;

  // Q into registers: rows q0+wave*16+r, all 512 K-elems (64 VGPR)
  bf16x8 q[16];
#pragma unroll
  for (int kk = 0; kk < 16; ++kk)
    q[kk] = *(const bf16x8*)(qp + (size_t)(q0 + wave * 16 + r) * 512 + kk * 32 + g * 8);

  // stage K,V tile t into buffer p: 64 gld_lds16 insts, 8 per wave
  auto stageKV = [&](int t, int p) {
    int kv = t * 32;
#pragma unroll
    for (int j = 0; j < 4; ++j) {
      int id = wave * 4 + j;  // 0..31
      int kk = id >> 1, f = id & 1;
      gld_lds16(kp + (size_t)(kv + f * 16 + r) * 512 + kk * 32 + g * 8,
                &Ks[p][(kk * 2 + f) * 64 * 8]);
    }
#pragma unroll
    for (int j = 0; j < 4; ++j) {
      int n = wave * 4 + j;  // 0..31
      gld_lds16(vp + (size_t)(n * 16 + r) * 1024 + kv + g * 8, &Vs[p][n * 64 * 8]);
    }
  };

  f32x4 o[32] = {};  // 16q x 512e per wave (128 VGPR)
  float mrun[4], lrun[4];
#pragma unroll
  for (int j = 0; j < 4; ++j) { mrun[j] = -1e30f; lrun[j] = 0.f; }

  stageKV(0, 0);

  for (int t = 0; t < 32; ++t) {
    const int p = t & 1;
    bar_vm0();  // stage(t) landed in LDS; all waves' LDS ops from iter t-1 done
    if (t < 31) stageKV(t + 1, p ^ 1);  // in flight across the lgkm-only barrier below

    // QK^T: S[16q x 32kv], two independent 16-deep chains
    f32x4 s0 = {}, s1 = {};
#pragma unroll
    for (int kk = 0; kk < 16; ++kk) {
      bf16x8 b0 = *(const bf16x8*)&Ks[p][((kk * 2 + 0) * 64 + lane) * 8];
      bf16x8 b1 = *(const bf16x8*)&Ks[p][((kk * 2 + 1) * 64 + lane) * 8];
      s0 = mfma_bf16(q[kk], b0, s0);
      s1 = mfma_bf16(q[kk], b1, s1);
    }

    // in-wave softmax (rows q=g*4+j, reduce over r)
    float gm[4];
    float growmax = -1e30f;
#pragma unroll
    for (int j = 0; j < 4; ++j) {
      s0[j] *= SCALE;
      s1[j] *= SCALE;
      float v = fmaxf(s0[j], s1[j]);
      v = fmaxf(v, __shfl_xor(v, 1));
      v = fmaxf(v, __shfl_xor(v, 2));
      v = fmaxf(v, __shfl_xor(v, 4));
      v = fmaxf(v, __shfl_xor(v, 8));
      gm[j] = v;
      growmax = fmaxf(growmax, v - mrun[j]);
    }
    if (__any(growmax > 6.0f)) {  // defer-max: rescale only when max grows
#pragma unroll
      for (int j = 0; j < 4; ++j) {
        float mn = fmaxf(mrun[j], gm[j]);
        float rsj = __expf(mrun[j] - mn);
        mrun[j] = mn;
        lrun[j] *= rsj;
#pragma unroll
        for (int n = 0; n < 32; ++n) o[n][j] *= rsj;
      }
    }
#pragma unroll
    for (int j = 0; j < 4; ++j) {
      float p0 = __expf(s0[j] - mrun[j]);
      float p1 = __expf(s1[j] - mrun[j]);
      float ls = p0 + p1;
      ls += __shfl_xor(ls, 1);
      ls += __shfl_xor(ls, 2);
      ls += __shfl_xor(ls, 4);
      ls += __shfl_xor(ls, 8);
      lrun[j] += ls;
      // P -> A-frag layout: elem(q,kv) at u16 index ((kv>>3)*16 + q)*8 + (kv&7)
      int qrow = g * 4 + j;
      Ps[wave][((r >> 3) * 16 + qrow) * 8 + (r & 7)] = f2bf(p0);        // kv = r
      Ps[wave][((2 + (r >> 3)) * 16 + qrow) * 8 + (r & 7)] = f2bf(p1);  // kv = 16+r
    }
    bar_lg0();  // Ps visible; prefetch vmem still in flight

    // PV: O[16q x 512e] += P[16q x 32kv] * V[32kv x 512e]
    bf16x8 pa = *(const bf16x8*)&Ps[wave][lane * 8];
#pragma unroll
    for (int n = 0; n < 32; ++n) {
      bf16x8 bv = *(const bf16x8*)&Vs[p][(n * 64 + lane) * 8];
      o[n] = mfma_bf16(pa, bv, o[n]);
    }
  }

  // normalize + write concat [B*S, 4096]
#pragma unroll
  for (int j = 0; j < 4; ++j) {
    float inv = 1.0f / lrun[j];
    int srow = q0 + wave * 16 + g * 4 + j;
    size_t rowoff = ((size_t)bb * 1024 + srow) * 4096;
#pragma unroll
    for (int n = 0; n < 32; ++n) {
      int ocol = hh * 512 + n * 16 + r;
      concat[rowoff + ocol] = f2bf(o[n][j] * inv);
    }
  }
}

// ---------------- residual add + layernorm (row of 512) ----------------
__global__ __launch_bounds__(128) void add_ln_kernel(const float* __restrict__ xin,
                                                     const float* __restrict__ addin,
                                                     const float* __restrict__ gamma,
                                                     const float* __restrict__ beta,
                                                     float* __restrict__ yout,
                                                     u16* __restrict__ ybout) {
  int row = blockIdx.x;
  int t = threadIdx.x;
  float4 xv = ((const float4*)(xin + (size_t)row * 512))[t];
  float4 av = ((const float4*)(addin + (size_t)row * 512))[t];
  float v0 = xv.x + av.x, v1 = xv.y + av.y, v2 = xv.z + av.z, v3 = xv.w + av.w;
  float s1 = v0 + v1 + v2 + v3;
  float s2 = v0 * v0 + v1 * v1 + v2 * v2 + v3 * v3;
#pragma unroll
  for (int d = 1; d < 64; d <<= 1) {
    s1 += __shfl_xor(s1, d);
    s2 += __shfl_xor(s2, d);
  }
  __shared__ float sh[4];
  int wv = t >> 6;
  if ((t & 63) == 0) { sh[wv * 2] = s1; sh[wv * 2 + 1] = s2; }
  __syncthreads();
  s1 = sh[0] + sh[2];
  s2 = sh[1] + sh[3];
  float mean = s1 * (1.0f / 512.0f);
  float var = s2 * (1.0f / 512.0f) - mean * mean;
  float rstd = rsqrtf(var + 1e-6f);
  float4 gv = ((const float4*)gamma)[t];
  float4 bv = ((const float4*)beta)[t];
  float o0 = (v0 - mean) * rstd * gv.x + bv.x;
  float o1 = (v1 - mean) * rstd * gv.y + bv.y;
  float o2 = (v2 - mean) * rstd * gv.z + bv.z;
  float o3 = (v3 - mean) * rstd * gv.w + bv.w;
  float4 ov; ov.x = o0; ov.y = o1; ov.z = o2; ov.w = o3;
  ((float4*)(yout + (size_t)row * 512))[t] = ov;
  if (ybout) {
    ushort4 ub;
    ub.x = f2bf(o0); ub.y = f2bf(o1); ub.z = f2bf(o2); ub.w = f2bf(o3);
    ((ushort4*)(ybout + (size_t)row * 512))[t] = ub;
  }
}

extern "C" void kernel_launch(void* const* d_in, const int* in_sizes, int n_in, void* d_out,
                              int out_size, void* d_ws, size_t ws_size, hipStream_t stream) {
  (void)in_sizes; (void)n_in; (void)out_size; (void)ws_size;
  const float* x   = (const float*)d_in[0];
  const float* Wq  = (const float*)d_in[1];
  const float* bq  = (const float*)d_in[2];
  const float* Wk  = (const float*)d_in[3];
  const float* bk  = (const float*)d_in[4];
  const float* Wv  = (const float*)d_in[5];
  const float* bv  = (const float*)d_in[6];
  const float* Wo  = (const float*)d_in[7];
  const float* bo  = (const float*)d_in[8];
  const float* g1  = (const float*)d_in[9];
  const float* be1 = (const float*)d_in[10];
  const float* W1  = (const float*)d_in[11];
  const float* b1  = (const float*)d_in[12];
  const float* W2  = (const float*)d_in[13];
  const float* b2  = (const float*)d_in[14];
  const float* g2  = (const float*)d_in[15];
  const float* be2 = (const float*)d_in[16];

  char* ws = (char*)d_ws;
  const size_t MB = 1024 * 1024;
  u16*   xb   = (u16*)(ws + 0);
  u16*   wqkT = (u16*)(ws + 4 * MB);
  u16*   wvT  = (u16*)(ws + 12 * MB);
  u16*   woT  = (u16*)(ws + 16 * MB);
  u16*   w1T  = (u16*)(ws + 20 * MB);
  u16*   w2T  = (u16*)(ws + 22 * MB);
  u16*   qb   = (u16*)(ws + 24 * MB);
  u16*   kb   = (u16*)(ws + 56 * MB);
  u16*   vTb  = (u16*)(ws + 88 * MB);
  u16*   cc   = (u16*)(ws + 120 * MB);
  float* mha  = (float*)(ws + 24 * MB);  // reuse q region after attention
  float* y    = (float*)(ws + 32 * MB);
  u16*   yb   = (u16*)(ws + 40 * MB);
  u16*   ff1  = (u16*)(ws + 56 * MB);    // reuse k region
  float* ff2  = (float*)(ws + 72 * MB);

  cvt_kernel<<<2048, 256, 0, stream>>>(x, xb, 524288);
  transpose_cvt<<<dim3(16, 16, 8), dim3(32, 8), 0, stream>>>(Wq, wqkT, 512, 512);
  transpose_cvt<<<dim3(16, 16, 8), dim3(32, 8), 0, stream>>>(Wk, wqkT + 8 * 512 * 512, 512, 512);
  transpose_cvt<<<dim3(16, 16, 8), dim3(32, 8), 0, stream>>>(Wv, wvT, 512, 512);
  transpose_cvt<<<dim3(16, 128, 1), dim3(32, 8), 0, stream>>>(Wo, woT, 4096, 512);
  transpose_cvt<<<dim3(64, 16, 1), dim3(32, 8), 0, stream>>>(W1, w1T, 512, 2048);
  transpose_cvt<<<dim3(16, 64, 1), dim3(32, 8), 0, stream>>>(W2, w2T, 2048, 512);

  gemm_tn<128, 128, 64, 64, 0><<<dim3(64, 32), 256, 0, stream>>>(xb, wqkT, 8192, 512, qb, kb, bq, bk);
  gemm_tn<128, 128, 64, 64, 1><<<dim3(32, 32), 256, 0, stream>>>(wvT, xb, 4096, 512, vTb, nullptr, bv, nullptr);
  flash_kernel<<<256, 512, 0, stream>>>(qb, kb, vTb, cc);
  gemm_tn<64, 128, 32, 64, 2><<<dim3(4, 64), 256, 0, stream>>>(cc, woT, 512, 4096, mha, nullptr, bo, nullptr);
  add_ln_kernel<<<4096, 128, 0, stream>>>(x, mha, g1, be1, y, yb);
  gemm_tn<128, 128, 64, 64, 3><<<dim3(16, 32), 256, 0, stream>>>(yb, w1T, 2048, 512, ff1, nullptr, b1, nullptr);
  gemm_tn<64, 128, 32, 64, 2><<<dim3(4, 64), 256, 0, stream>>>(ff1, w2T, 512, 2048, ff2, nullptr, b2, nullptr);
  add_ln_kernel<<<4096, 128, 0, stream>>>(y, ff2, g2, be2, (float*)d_out, nullptr);
}

// Round 4
// 377.140 us; speedup vs baseline: 1.6246x; 1.0659x over previous
//
#include <hip/hip_runtime.h>
#include <hip/hip_bf16.h>

typedef unsigned short u16;
typedef __attribute__((ext_vector_type(4))) float f32x4;
typedef __attribute__((ext_vector_type(8))) __bf16 bf16x8;

#define DEV __device__ __forceinline__

DEV u16 f2bf(float f) {
  union { float f; unsigned u; } c; c.f = f;
  unsigned r = (c.u + 0x7fffu + ((c.u >> 16) & 1u)) >> 16;
  return (u16)r;
}

DEV void gld_lds16(const void* g, void* l) {
  __builtin_amdgcn_global_load_lds(
      (__attribute__((address_space(1))) void*)g,
      (__attribute__((address_space(3))) void*)l, 16, 0, 0);
}

DEV f32x4 mfma_bf16(bf16x8 a, bf16x8 b, f32x4 c) {
  return __builtin_amdgcn_mfma_f32_16x16x32_bf16(a, b, c, 0, 0, 0);
}

// raw barrier that does NOT drain prefetch unless asked
DEV void bar_vm0() { asm volatile("s_waitcnt vmcnt(0) lgkmcnt(0)\n\ts_barrier" ::: "memory"); }
DEV void wait_lg0() { asm volatile("s_waitcnt lgkmcnt(0)" ::: "memory"); }

// ---------------- convert f32 -> bf16 (vectorized) ----------------
__global__ __launch_bounds__(256) void cvt_kernel(const float* __restrict__ in,
                                                  u16* __restrict__ out, int n4) {
  int i = blockIdx.x * 256 + threadIdx.x;
  if (i < n4) {
    float4 v = ((const float4*)in)[i];
    ushort4 o;
    o.x = f2bf(v.x); o.y = f2bf(v.y); o.z = f2bf(v.z); o.w = f2bf(v.w);
    ((ushort4*)out)[i] = o;
  }
}

// ------------- transpose + convert: in f32 [bz][R][C] -> out bf16 [bz][C][R] -------------
__global__ __launch_bounds__(256) void transpose_cvt(const float* __restrict__ in,
                                                     u16* __restrict__ out, int R, int C) {
  __shared__ float t[32][33];
  size_t base = (size_t)blockIdx.z * R * C;
  const float* ip = in + base;
  u16* op = out + base;
  int c0 = blockIdx.x * 32, r0 = blockIdx.y * 32;
  int tx = threadIdx.x, ty = threadIdx.y;
#pragma unroll
  for (int i = 0; i < 4; ++i) {
    int rr = ty + i * 8;
    t[rr][tx] = ip[(size_t)(r0 + rr) * C + c0 + tx];
  }
  __syncthreads();
#pragma unroll
  for (int i = 0; i < 4; ++i) {
    int cc = ty + i * 8;
    op[(size_t)(c0 + cc) * R + r0 + tx] = f2bf(t[tx][cc]);
  }
}

// ---------------- generic TN bf16 GEMM: C = A[M,K] * B[N,K]^T ----------------
template <int BM, int BN, int WM, int WN, int MODE>
__global__ __launch_bounds__(256) void gemm_tn(const u16* __restrict__ A,
                                               const u16* __restrict__ B, int N, int K,
                                               void* __restrict__ out0, void* __restrict__ out1,
                                               const float* __restrict__ bias0,
                                               const float* __restrict__ bias1) {
  constexpr int BK = 64;
  constexpr int MF = WM / 16, NF = WN / 16;
  constexpr int WC = BN / WN;
  __shared__ u16 As[BM * BK];
  __shared__ u16 Bs[BN * BK];
  const int tid = threadIdx.x;
  const int wave = tid >> 6, lane = tid & 63;
  const int r = lane & 15, g = lane >> 4;
  const int row0 = blockIdx.y * BM, col0 = blockIdx.x * BN;
  const int wr = (wave / WC) * WM, wc = (wave % WC) * WN;

  f32x4 acc[MF][NF] = {};

  for (int kt = 0; kt < K; kt += BK) {
#pragma unroll
    for (int i = 0; i < (BM * BK / 8) / 256; ++i) {
      int c = i * 256 + wave * 64 + lane;
      gld_lds16(A + (size_t)(row0 + (c >> 3)) * K + kt + (c & 7) * 8,
                As + (size_t)(i * 256 + wave * 64) * 8);
    }
#pragma unroll
    for (int i = 0; i < (BN * BK / 8) / 256; ++i) {
      int c = i * 256 + wave * 64 + lane;
      gld_lds16(B + (size_t)(col0 + (c >> 3)) * K + kt + (c & 7) * 8,
                Bs + (size_t)(i * 256 + wave * 64) * 8);
    }
    __syncthreads();
#pragma unroll
    for (int kk = 0; kk < 2; ++kk) {
      bf16x8 af[MF], bfv[NF];
#pragma unroll
      for (int m = 0; m < MF; ++m)
        af[m] = *(const bf16x8*)(As + (wr + m * 16 + r) * BK + kk * 32 + g * 8);
#pragma unroll
      for (int n = 0; n < NF; ++n)
        bfv[n] = *(const bf16x8*)(Bs + (wc + n * 16 + r) * BK + kk * 32 + g * 8);
#pragma unroll
      for (int m = 0; m < MF; ++m)
#pragma unroll
        for (int n = 0; n < NF; ++n)
          acc[m][n] = mfma_bf16(af[m], bfv[n], acc[m][n]);
    }
    __syncthreads();
  }

#pragma unroll
  for (int m = 0; m < MF; ++m) {
#pragma unroll
    for (int n = 0; n < NF; ++n) {
      int gcol = col0 + wc + n * 16 + r;
#pragma unroll
      for (int j = 0; j < 4; ++j) {
        int grow = row0 + wr + m * 16 + g * 4 + j;
        float val = acc[m][n][j];
        if constexpr (MODE == 0) {
          int p = gcol >> 12;
          int he = gcol & 4095;
          u16* dst = (u16*)(p ? out1 : out0);
          const float* bsp = p ? bias1 : bias0;
          val += bsp[he];
          int bb = grow >> 10, s = grow & 1023;
          size_t off = (((size_t)(bb * 8 + (he >> 9)) * 1024 + s) * 512) + (he & 511);
          dst[off] = f2bf(val);
        } else if constexpr (MODE == 1) {
          val += bias0[grow];
          int bb = gcol >> 10, s = gcol & 1023;
          size_t off = (((size_t)bb * 8 + (grow >> 9)) * 512 + (grow & 511)) * 1024 + s;
          ((u16*)out0)[off] = f2bf(val);
        } else if constexpr (MODE == 2) {
          ((float*)out0)[(size_t)grow * N + gcol] = val + bias0[gcol];
        } else {
          float v2 = fmaxf(val + bias0[gcol], 0.0f);
          ((u16*)out0)[(size_t)grow * N + gcol] = f2bf(v2);
        }
      }
    }
  }
  (void)out1; (void)bias1;
}

// ---------------- flash attention (v5) ----------------
// 256 blocks (1/CU), XCD-swizzled. 8 waves x 16 q-rows x full 512 e.
// 64B-coalesced staging (4 lanes per row -> full cache line), one barrier/iter,
// 4 independent QK accumulator chains, setprio around MFMA clusters.
__global__ __launch_bounds__(512, 2) void flash_kernel(const u16* __restrict__ qg,
                                                       const u16* __restrict__ kg,
                                                       const u16* __restrict__ vtg,
                                                       u16* __restrict__ concat) {
  constexpr float SCALE = 0.04419417382415922f;  // 1/sqrt(512)
  // per buffer 32KB = 32 insts x 512 u16; frag (r,g) at inst_base + (r*4+g)*8
  __shared__ u16 Ks[2][32 * 512];
  __shared__ u16 Vs[2][32 * 512];
  __shared__ u16 Ps[8][512];

  const int tid = threadIdx.x;
  const int wave = tid >> 6, lane = tid & 63;
  const int r = lane & 15, g = lane >> 4;
  const int l4 = lane >> 2, lc = lane & 3;  // staging: row-sub, 64B-chunk
  const int bx = blockIdx.x;
  const int xcd = bx & 7, slot = bx >> 3;
  const int bh = xcd * 4 + (slot >> 3);
  const int qt = slot & 7;
  const int bb = bh >> 3, hh = bh & 7;
  const size_t hbase = (size_t)bh * 1024 * 512;
  const u16* qp = qg + hbase;
  const u16* kp = kg + hbase;
  const u16* vp = vtg + hbase;  // V^T [512][1024] per head
  const int q0 = qt * 128;

  // Q into registers: rows q0+wave*16+r, all 512 K-elems (64 VGPR)
  bf16x8 q[16];
#pragma unroll
  for (int kk = 0; kk < 16; ++kk)
    q[kk] = *(const bf16x8*)(qp + (size_t)(q0 + wave * 16 + r) * 512 + kk * 32 + g * 8);

  // stage K,V tile t into buffer p: 64 gld_lds16, 8 per wave, 64B/row coalesced
  auto stageKV = [&](int t, int p) {
    int kv = t * 32;
#pragma unroll
    for (int j = 0; j < 4; ++j) {
      int id = wave * 4 + j;           // 0..31 = kc*2 + rh
      int kc = id >> 1, rh = id & 1;   // k-chunk of 32, kv-row-half of 16
      gld_lds16(kp + (size_t)(kv + rh * 16 + l4) * 512 + kc * 32 + lc * 8,
                &Ks[p][id * 512]);
    }
#pragma unroll
    for (int j = 0; j < 4; ++j) {
      int n = wave * 4 + j;            // e-row group 0..31
      gld_lds16(vp + (size_t)(n * 16 + l4) * 1024 + kv + lc * 8, &Vs[p][n * 512]);
    }
  };

  f32x4 o[32] = {};  // 16q x 512e per wave (128 VGPR)
  float mrun[4], lrun[4];
#pragma unroll
  for (int j = 0; j < 4; ++j) { mrun[j] = -1e30f; lrun[j] = 0.f; }

  stageKV(0, 0);

  const int fo = (r * 4 + g) * 8;  // fragment offset within a 512-u16 inst slot

  for (int t = 0; t < 32; ++t) {
    const int p = t & 1;
    bar_vm0();  // stage(t) landed; all waves done reading buffer p from iter t-2
    if (t < 31) stageKV(t + 1, p ^ 1);  // stays in flight until next top barrier

    // QK^T: S[16q x 32kv], 4 independent 8-deep chains
    __builtin_amdgcn_s_setprio(1);
    f32x4 sA = {}, sB = {}, sC = {}, sD = {};
#pragma unroll
    for (int kk = 0; kk < 8; ++kk) {
      bf16x8 b00 = *(const bf16x8*)&Ks[p][(kk * 4 + 0) * 512 + fo];
      bf16x8 b01 = *(const bf16x8*)&Ks[p][(kk * 4 + 1) * 512 + fo];
      bf16x8 b10 = *(const bf16x8*)&Ks[p][(kk * 4 + 2) * 512 + fo];
      bf16x8 b11 = *(const bf16x8*)&Ks[p][(kk * 4 + 3) * 512 + fo];
      sA = mfma_bf16(q[2 * kk], b00, sA);
      sB = mfma_bf16(q[2 * kk], b01, sB);
      sC = mfma_bf16(q[2 * kk + 1], b10, sC);
      sD = mfma_bf16(q[2 * kk + 1], b11, sD);
    }
    __builtin_amdgcn_s_setprio(0);
    f32x4 s0 = sA + sC;  // kv = r
    f32x4 s1 = sB + sD;  // kv = 16 + r

    // in-wave softmax (rows q=g*4+j, reduce over r)
    float gm[4];
    float growmax = -1e30f;
#pragma unroll
    for (int j = 0; j < 4; ++j) {
      s0[j] *= SCALE;
      s1[j] *= SCALE;
      float v = fmaxf(s0[j], s1[j]);
      v = fmaxf(v, __shfl_xor(v, 1));
      v = fmaxf(v, __shfl_xor(v, 2));
      v = fmaxf(v, __shfl_xor(v, 4));
      v = fmaxf(v, __shfl_xor(v, 8));
      gm[j] = v;
      growmax = fmaxf(growmax, v - mrun[j]);
    }
    if (__any(growmax > 6.0f)) {  // defer-max: rescale only when max grows
#pragma unroll
      for (int j = 0; j < 4; ++j) {
        float mn = fmaxf(mrun[j], gm[j]);
        float rsj = __expf(mrun[j] - mn);
        mrun[j] = mn;
        lrun[j] *= rsj;
#pragma unroll
        for (int n = 0; n < 32; ++n) o[n][j] *= rsj;
      }
    }
#pragma unroll
    for (int j = 0; j < 4; ++j) {
      float p0 = __expf(s0[j] - mrun[j]);
      float p1 = __expf(s1[j] - mrun[j]);
      float ls = p0 + p1;
      ls += __shfl_xor(ls, 1);
      ls += __shfl_xor(ls, 2);
      ls += __shfl_xor(ls, 4);
      ls += __shfl_xor(ls, 8);
      lrun[j] += ls;
      // P -> A-frag layout: elem(q,kv) at u16 index ((kv>>3)*16 + q)*8 + (kv&7)
      int qrow = g * 4 + j;
      Ps[wave][((r >> 3) * 16 + qrow) * 8 + (r & 7)] = f2bf(p0);        // kv = r
      Ps[wave][((2 + (r >> 3)) * 16 + qrow) * 8 + (r & 7)] = f2bf(p1);  // kv = 16+r
    }
    wait_lg0();  // own Ps writes visible to own reads; NO barrier (Ps is wave-private)

    // PV: O[16q x 512e] += P[16q x 32kv] * V[32kv x 512e]
    bf16x8 pa = *(const bf16x8*)&Ps[wave][lane * 8];
    __builtin_amdgcn_s_setprio(1);
#pragma unroll
    for (int n = 0; n < 32; ++n) {
      bf16x8 bv = *(const bf16x8*)&Vs[p][n * 512 + fo];
      o[n] = mfma_bf16(pa, bv, o[n]);
    }
    __builtin_amdgcn_s_setprio(0);
  }

  // normalize + write concat [B*S, 4096]
#pragma unroll
  for (int j = 0; j < 4; ++j) {
    float inv = 1.0f / lrun[j];
    int srow = q0 + wave * 16 + g * 4 + j;
    size_t rowoff = ((size_t)bb * 1024 + srow) * 4096;
#pragma unroll
    for (int n = 0; n < 32; ++n) {
      int ocol = hh * 512 + n * 16 + r;
      concat[rowoff + ocol] = f2bf(o[n][j] * inv);
    }
  }
}

// ---------------- residual add + layernorm (row of 512) ----------------
__global__ __launch_bounds__(128) void add_ln_kernel(const float* __restrict__ xin,
                                                     const float* __restrict__ addin,
                                                     const float* __restrict__ gamma,
                                                     const float* __restrict__ beta,
                                                     float* __restrict__ yout,
                                                     u16* __restrict__ ybout) {
  int row = blockIdx.x;
  int t = threadIdx.x;
  float4 xv = ((const float4*)(xin + (size_t)row * 512))[t];
  float4 av = ((const float4*)(addin + (size_t)row * 512))[t];
  float v0 = xv.x + av.x, v1 = xv.y + av.y, v2 = xv.z + av.z, v3 = xv.w + av.w;
  float s1 = v0 + v1 + v2 + v3;
  float s2 = v0 * v0 + v1 * v1 + v2 * v2 + v3 * v3;
#pragma unroll
  for (int d = 1; d < 64; d <<= 1) {
    s1 += __shfl_xor(s1, d);
    s2 += __shfl_xor(s2, d);
  }
  __shared__ float sh[4];
  int wv = t >> 6;
  if ((t & 63) == 0) { sh[wv * 2] = s1; sh[wv * 2 + 1] = s2; }
  __syncthreads();
  s1 = sh[0] + sh[2];
  s2 = sh[1] + sh[3];
  float mean = s1 * (1.0f / 512.0f);
  float var = s2 * (1.0f / 512.0f) - mean * mean;
  float rstd = rsqrtf(var + 1e-6f);
  float4 gv = ((const float4*)gamma)[t];
  float4 bv = ((const float4*)beta)[t];
  float o0 = (v0 - mean) * rstd * gv.x + bv.x;
  float o1 = (v1 - mean) * rstd * gv.y + bv.y;
  float o2 = (v2 - mean) * rstd * gv.z + bv.z;
  float o3 = (v3 - mean) * rstd * gv.w + bv.w;
  float4 ov; ov.x = o0; ov.y = o1; ov.z = o2; ov.w = o3;
  ((float4*)(yout + (size_t)row * 512))[t] = ov;
  if (ybout) {
    ushort4 ub;
    ub.x = f2bf(o0); ub.y = f2bf(o1); ub.z = f2bf(o2); ub.w = f2bf(o3);
    ((ushort4*)(ybout + (size_t)row * 512))[t] = ub;
  }
}

extern "C" void kernel_launch(void* const* d_in, const int* in_sizes, int n_in, void* d_out,
                              int out_size, void* d_ws, size_t ws_size, hipStream_t stream) {
  (void)in_sizes; (void)n_in; (void)out_size; (void)ws_size;
  const float* x   = (const float*)d_in[0];
  const float* Wq  = (const float*)d_in[1];
  const float* bq  = (const float*)d_in[2];
  const float* Wk  = (const float*)d_in[3];
  const float* bk  = (const float*)d_in[4];
  const float* Wv  = (const float*)d_in[5];
  const float* bv  = (const float*)d_in[6];
  const float* Wo  = (const float*)d_in[7];
  const float* bo  = (const float*)d_in[8];
  const float* g1  = (const float*)d_in[9];
  const float* be1 = (const float*)d_in[10];
  const float* W1  = (const float*)d_in[11];
  const float* b1  = (const float*)d_in[12];
  const float* W2  = (const float*)d_in[13];
  const float* b2  = (const float*)d_in[14];
  const float* g2  = (const float*)d_in[15];
  const float* be2 = (const float*)d_in[16];

  char* ws = (char*)d_ws;
  const size_t MB = 1024 * 1024;
  u16*   xb   = (u16*)(ws + 0);
  u16*   wqkT = (u16*)(ws + 4 * MB);
  u16*   wvT  = (u16*)(ws + 12 * MB);
  u16*   woT  = (u16*)(ws + 16 * MB);
  u16*   w1T  = (u16*)(ws + 20 * MB);
  u16*   w2T  = (u16*)(ws + 22 * MB);
  u16*   qb   = (u16*)(ws + 24 * MB);
  u16*   kb   = (u16*)(ws + 56 * MB);
  u16*   vTb  = (u16*)(ws + 88 * MB);
  u16*   cc   = (u16*)(ws + 120 * MB);
  float* mha  = (float*)(ws + 24 * MB);  // reuse q region after attention
  float* y    = (float*)(ws + 32 * MB);
  u16*   yb   = (u16*)(ws + 40 * MB);
  u16*   ff1  = (u16*)(ws + 56 * MB);    // reuse k region
  float* ff2  = (float*)(ws + 72 * MB);

  cvt_kernel<<<2048, 256, 0, stream>>>(x, xb, 524288);
  transpose_cvt<<<dim3(16, 16, 8), dim3(32, 8), 0, stream>>>(Wq, wqkT, 512, 512);
  transpose_cvt<<<dim3(16, 16, 8), dim3(32, 8), 0, stream>>>(Wk, wqkT + 8 * 512 * 512, 512, 512);
  transpose_cvt<<<dim3(16, 16, 8), dim3(32, 8), 0, stream>>>(Wv, wvT, 512, 512);
  transpose_cvt<<<dim3(16, 128, 1), dim3(32, 8), 0, stream>>>(Wo, woT, 4096, 512);
  transpose_cvt<<<dim3(64, 16, 1), dim3(32, 8), 0, stream>>>(W1, w1T, 512, 2048);
  transpose_cvt<<<dim3(16, 64, 1), dim3(32, 8), 0, stream>>>(W2, w2T, 2048, 512);

  gemm_tn<128, 128, 64, 64, 0><<<dim3(64, 32), 256, 0, stream>>>(xb, wqkT, 8192, 512, qb, kb, bq, bk);
  gemm_tn<128, 128, 64, 64, 1><<<dim3(32, 32), 256, 0, stream>>>(wvT, xb, 4096, 512, vTb, nullptr, bv, nullptr);
  flash_kernel<<<256, 512, 0, stream>>>(qb, kb, vTb, cc);
  gemm_tn<64, 128, 32, 64, 2><<<dim3(4, 64), 256, 0, stream>>>(cc, woT, 512, 4096, mha, nullptr, bo, nullptr);
  add_ln_kernel<<<4096, 128, 0, stream>>>(x, mha, g1, be1, y, yb);
  gemm_tn<128, 128, 64, 64, 3><<<dim3(16, 32), 256, 0, stream>>>(yb, w1T, 2048, 512, ff1, nullptr, b1, nullptr);
  gemm_tn<64, 128, 32, 64, 2><<<dim3(4, 64), 256, 0, stream>>>(ff1, w2T, 512, 2048, ff2, nullptr, b2, nullptr);
  add_ln_kernel<<<4096, 128, 0, stream>>>(y, ff2, g2, be2, (float*)d_out, nullptr);
}